// Round 1
// 304.831 us; speedup vs baseline: 1.0687x; 1.0687x over previous
//
#include <hip/hip_runtime.h>
#include <hip/hip_fp16.h>

// GCN forward: 3x (GEMM -> normalized scatter-sum -> bias -> relu[except last])
// Gather table and agg<->gemm interfaces are fp16. ep = (src, norm) int2 —
// precomputed norm (R6: per-edge dinv gathers regress). CSR built with zero
// global atomics. R8: GEMMs moved to MFMA (v_mfma_f32_16x16x32_f16), swapped
// operands (W in A slot) so each lane stores 8 contiguous bytes; W staged
// once into LDS pre-swizzled into fragment order (no syncs in K loop); X
// streamed from global (each element read exactly once).

#define ALIGN256(x) (((size_t)(x) + 255) & ~(size_t)255)

typedef _Float16 f16;
typedef f16 f16x8 __attribute__((ext_vector_type(8)));
typedef float f32x4 __attribute__((ext_vector_type(4)));

// ---------------- coarse histogram ----------------

__global__ __launch_bounds__(256) void k_coarse(const int* __restrict__ ei,
                                                int* __restrict__ ccnt,
                                                int E, int NBUK) {
    __shared__ int h[512];
    int t = threadIdx.x;
    for (int i = t; i < NBUK; i += 256) h[i] = 0;
    __syncthreads();
    int e0 = blockIdx.x * 8192;
    int e1 = min(e0 + 8192, E);
    for (int e = e0 + t; e < e1; e += 256) atomicAdd(&h[ei[E + e] >> 8], 1);
    __syncthreads();
    for (int i = t; i < NBUK; i += 256) {
        int c = h[i];
        if (c) atomicAdd(&ccnt[i], c);
    }
}

// ---------------- scan of coarse counts (single block, <=512 buckets) -------

__global__ __launch_bounds__(256) void k_cscan(const int* __restrict__ ccnt,
                                               int* __restrict__ cbase,
                                               int* __restrict__ cpos,
                                               int* __restrict__ row_start,
                                               int NBUK, int E, int N) {
    __shared__ int sd[256];
    int t = threadIdx.x;
    int i0 = 2 * t, i1 = 2 * t + 1;
    int v0 = (i0 < NBUK) ? ccnt[i0] : 0;
    int v1 = (i1 < NBUK) ? ccnt[i1] : 0;
    int s = v0 + v1;
    sd[t] = s;
    __syncthreads();
    for (int off = 1; off < 256; off <<= 1) {
        int u = (t >= off) ? sd[t - off] : 0;
        __syncthreads();
        sd[t] += u;
        __syncthreads();
    }
    int base = sd[t] - s;
    if (i0 < NBUK) { cbase[i0] = base;      cpos[i0] = base; }
    if (i1 < NBUK) { cbase[i1] = base + v0; cpos[i1] = base + v0; }
    if (t == 0) { cbase[NBUK] = E; row_start[N] = E; }
}

// ---------------- pass A: coarse scatter; stage entry = (dst&255)<<24 | src -

__global__ __launch_bounds__(256) void k_passA(const int* __restrict__ ei,
                                               int* __restrict__ cpos,
                                               unsigned int* __restrict__ stage,
                                               int E, int NBUK) {
    __shared__ int h[512];
    __shared__ int base[512];
    int t = threadIdx.x;
    for (int i = t; i < NBUK; i += 256) h[i] = 0;
    __syncthreads();
    int e0 = blockIdx.x * 8192;
    int e1 = min(e0 + 8192, E);
    for (int e = e0 + t; e < e1; e += 256) atomicAdd(&h[ei[E + e] >> 8], 1);
    __syncthreads();
    for (int b = t; b < NBUK; b += 256) {
        int c = h[b];
        base[b] = c ? atomicAdd(&cpos[b], c) : 0;
        h[b] = 0;
    }
    __syncthreads();
    for (int e = e0 + t; e < e1; e += 256) {
        unsigned int s = (unsigned int)ei[e];
        int d = ei[E + e];
        int b = d >> 8;
        int off = base[b] + atomicAdd(&h[b], 1);
        stage[off] = ((unsigned int)(d & 255) << 24) | s;
    }
}

// ---------------- B1: per-bucket node counts (LDS atomics) -> row_start, dinv

__global__ __launch_bounds__(256) void k_B1(const unsigned int* __restrict__ stage,
                                            const int* __restrict__ cbase,
                                            int* __restrict__ row_start,
                                            float* __restrict__ dinv, int N) {
    __shared__ int cnt[256];
    __shared__ int sd[256];
    int b = blockIdx.x;
    int n0 = b << 8;
    int t = threadIdx.x;
    cnt[t] = 0;
    __syncthreads();
    int s0 = cbase[b], s1 = cbase[b + 1];
    for (int j = s0 + t; j < s1; j += 256) atomicAdd(&cnt[stage[j] >> 24], 1);
    __syncthreads();
    int c = cnt[t];
    sd[t] = c;
    __syncthreads();
    for (int off = 1; off < 256; off <<= 1) {
        int u = (t >= off) ? sd[t - off] : 0;
        __syncthreads();
        sd[t] += u;
        __syncthreads();
    }
    int excl = sd[t] - c;
    int node = n0 + t;
    if (node < N) {
        row_start[node] = s0 + excl;
        dinv[node] = 1.0f / sqrtf((float)(c + 1));   // +1 self-loop
    }
}

// ---------------- B2: fine scatter within bucket -> ep = (src, norm) --------

__global__ __launch_bounds__(256) void k_B2(const unsigned int* __restrict__ stage,
                                            const int* __restrict__ cbase,
                                            const int* __restrict__ row_start,
                                            const float* __restrict__ dinv,
                                            int2* __restrict__ ep, int N) {
    __shared__ int lpos[256];
    __shared__ float ld[256];
    int b = blockIdx.x;
    int n0 = b << 8;
    int t = threadIdx.x;
    int node = n0 + t;
    if (node < N) {
        lpos[t] = row_start[node];
        ld[t] = dinv[node];
    }
    __syncthreads();
    int s0 = cbase[b], s1 = cbase[b + 1];
    for (int j = s0 + t; j < s1; j += 256) {
        unsigned int v = stage[j];
        int li = v >> 24;
        int src = v & 0xFFFFFF;
        int slot = atomicAdd(&lpos[li], 1);
        ep[slot] = make_int2(src, __float_as_int(dinv[src] * ld[li]));
    }
}

// ---------------- MFMA GEMM: Y[N,OUT](fp16) = X[N,K] @ W[K,OUT] -------------
// Block = 256 thr = 4 waves; block covers 64 rows (16 per wave), all OUT cols
// via NF=ceil(OUT/16) column fragments. v_mfma_f32_16x16x32_f16, fp32 accum.
// SWAPPED operands: W fragment is the A (M) operand, X rows the B (N) operand,
// so D maps row=lane&15, cols=4*(lane>>4)+reg -> 8B-contiguous stores.
// k-fill uses k = 8h+j for BOTH operands: any bijection shared by A and B
// yields a correct dot product (permutation invariance), so the exact HW k
// order doesn't matter. W staged to LDS once, pre-swizzled so fragment loads
// are conflict-free ds_read_b128; NO barrier inside the K loop. X is read
// straight from global: each element touched exactly once on the whole chip.

template <int K, int OUT, int NF, typename XT>
__global__ __launch_bounds__(256) void k_mgemm(const XT* __restrict__ X,
                                               const float* __restrict__ W,
                                               __half* __restrict__ Y, int N) {
    constexpr int NC = NF * 16;     // padded col count
    constexpr int NT = K / 32;      // k-steps
    __shared__ f16 Wl[NT * NF * 4 * 128];   // [t][f][h][nn][j], 16B/fragment

    int tid = threadIdx.x;
    // stage W (swizzled into fragment order), zero-pad cols >= OUT
    for (int idx = tid; idx < K * NC; idx += 256) {
        int k = idx / NC;
        int n = idx - k * NC;
        float v = (n < OUT) ? W[k * OUT + n] : 0.0f;
        int t = k >> 5, h = (k >> 3) & 3, j = k & 7, f = n >> 4, nn = n & 15;
        Wl[((t * NF + f) * 4 + h) * 128 + nn * 8 + j] = (f16)v;
    }
    __syncthreads();

    int lane = tid & 63;
    int wid = tid >> 6;
    int h = lane >> 4;          // k-subblock selector (k = 8h+j)
    int nn = lane & 15;         // output row within wave tile
    int row = blockIdx.x * 64 + (wid << 4) + nn;
    bool valid = row < N;

    f32x4 acc[NF];
#pragma unroll
    for (int f = 0; f < NF; ++f) acc[f] = (f32x4){0.f, 0.f, 0.f, 0.f};

#pragma unroll
    for (int t = 0; t < NT; ++t) {
        f16x8 xf;
        if (valid) {
            if constexpr (sizeof(XT) == 4) {
                const float* xp = (const float*)X + (size_t)row * K + (t << 5) + (h << 3);
                float4 u0 = *(const float4*)xp;
                float4 u1 = *(const float4*)(xp + 4);
                xf[0] = (f16)u0.x; xf[1] = (f16)u0.y; xf[2] = (f16)u0.z; xf[3] = (f16)u0.w;
                xf[4] = (f16)u1.x; xf[5] = (f16)u1.y; xf[6] = (f16)u1.z; xf[7] = (f16)u1.w;
            } else {
                xf = *(const f16x8*)((const __half*)X + (size_t)row * K + (t << 5) + (h << 3));
            }
        } else {
#pragma unroll
            for (int j = 0; j < 8; ++j) xf[j] = (f16)0.f;
        }
#pragma unroll
        for (int f = 0; f < NF; ++f) {
            f16x8 wf = *(const f16x8*)&Wl[((t * NF + f) * 4 + h) * 128 + nn * 8];
            acc[f] = __builtin_amdgcn_mfma_f32_16x16x32_f16(wf, xf, acc[f], 0, 0, 0);
        }
    }

    if (valid) {
#pragma unroll
        for (int f = 0; f < NF; ++f) {
            int c = (f << 4) + (h << 2);    // 4 consecutive cols c..c+3
            if (c < OUT) {
                __half2 p0 = __floats2half2_rn(acc[f][0], acc[f][1]);
                __half2 p1 = __floats2half2_rn(acc[f][2], acc[f][3]);
                uint2 pk = make_uint2(*(unsigned int*)&p0, *(unsigned int*)&p1);
                *(uint2*)&Y[(size_t)row * OUT + c] = pk;
            }
        }
    }
}

// ---------------- Aggregation (fp16 gather, fp32 accumulate) ----------------
// 8 lanes/node (lane = 8 fp16 feats = 16B), 8 nodes/wave, unroll x8:
// up to 64 independent 16B gathers in flight per wave. ep = (src,norm) int2.

__device__ __forceinline__ void fma8(float4& a0, float4& a1, uint4 hv, float w) {
    __half2* hp = (__half2*)&hv;
    float2 f0 = __half22float2(hp[0]);
    float2 f1 = __half22float2(hp[1]);
    float2 f2 = __half22float2(hp[2]);
    float2 f3 = __half22float2(hp[3]);
    a0.x += f0.x * w; a0.y += f0.y * w; a0.z += f1.x * w; a0.w += f1.y * w;
    a1.x += f2.x * w; a1.y += f2.y * w; a1.z += f3.x * w; a1.w += f3.y * w;
}

template <int NV, int F, int RELU, typename OutT>
__global__ __launch_bounds__(256) void k_agg(const __half* __restrict__ H,
                                             const int* __restrict__ row_start,
                                             const int2* __restrict__ ep,
                                             const float* __restrict__ dinv,
                                             const float* __restrict__ bias,
                                             OutT* __restrict__ out, int N) {
    int tid = threadIdx.x;
    int lane = tid & 63;
    int sub = lane >> 3;        // node within wave (0..7)
    int lq = lane & 7;          // 8-feature chunk
    int node = blockIdx.x * 32 + (tid >> 6) * 8 + sub;
    if (node >= N) return;
    const bool act = (NV == 8) || (lq < NV);

    int jb = row_start[node];
    int je = row_start[node + 1];
    float dv = dinv[node];

    float4 a0 = make_float4(0.f, 0.f, 0.f, 0.f);
    float4 a1 = make_float4(0.f, 0.f, 0.f, 0.f);
    if (act) {
        uint4 hv = *(const uint4*)&H[(size_t)node * F + 8 * lq];
        fma8(a0, a1, hv, dv * dv);
    }

    int j = jb;
    for (; j + 8 <= je; j += 8) {
        int2 e0 = ep[j],     e1 = ep[j + 1], e2 = ep[j + 2], e3 = ep[j + 3];
        int2 e4 = ep[j + 4], e5 = ep[j + 5], e6 = ep[j + 6], e7 = ep[j + 7];
        if (act) {
            uint4 h0 = *(const uint4*)&H[(size_t)e0.x * F + 8 * lq];
            uint4 h1 = *(const uint4*)&H[(size_t)e1.x * F + 8 * lq];
            uint4 h2 = *(const uint4*)&H[(size_t)e2.x * F + 8 * lq];
            uint4 h3 = *(const uint4*)&H[(size_t)e3.x * F + 8 * lq];
            uint4 h4 = *(const uint4*)&H[(size_t)e4.x * F + 8 * lq];
            uint4 h5 = *(const uint4*)&H[(size_t)e5.x * F + 8 * lq];
            uint4 h6 = *(const uint4*)&H[(size_t)e6.x * F + 8 * lq];
            uint4 h7 = *(const uint4*)&H[(size_t)e7.x * F + 8 * lq];
            fma8(a0, a1, h0, __int_as_float(e0.y));
            fma8(a0, a1, h1, __int_as_float(e1.y));
            fma8(a0, a1, h2, __int_as_float(e2.y));
            fma8(a0, a1, h3, __int_as_float(e3.y));
            fma8(a0, a1, h4, __int_as_float(e4.y));
            fma8(a0, a1, h5, __int_as_float(e5.y));
            fma8(a0, a1, h6, __int_as_float(e6.y));
            fma8(a0, a1, h7, __int_as_float(e7.y));
        }
    }
    for (; j + 2 <= je; j += 2) {
        int2 e0 = ep[j], e1 = ep[j + 1];
        if (act) {
            uint4 h0 = *(const uint4*)&H[(size_t)e0.x * F + 8 * lq];
            uint4 h1 = *(const uint4*)&H[(size_t)e1.x * F + 8 * lq];
            fma8(a0, a1, h0, __int_as_float(e0.y));
            fma8(a0, a1, h1, __int_as_float(e1.y));
        }
    }
    if (j < je) {
        int2 e = ep[j];
        if (act) {
            uint4 h = *(const uint4*)&H[(size_t)e.x * F + 8 * lq];
            fma8(a0, a1, h, __int_as_float(e.y));
        }
    }

    if (act) {
        float4 b0 = *(const float4*)&bias[8 * lq];
        float4 b1 = *(const float4*)&bias[8 * lq + 4];
        a0.x += b0.x; a0.y += b0.y; a0.z += b0.z; a0.w += b0.w;
        a1.x += b1.x; a1.y += b1.y; a1.z += b1.z; a1.w += b1.w;
        if (RELU) {
            a0.x = fmaxf(a0.x, 0.f); a0.y = fmaxf(a0.y, 0.f);
            a0.z = fmaxf(a0.z, 0.f); a0.w = fmaxf(a0.w, 0.f);
            a1.x = fmaxf(a1.x, 0.f); a1.y = fmaxf(a1.y, 0.f);
            a1.z = fmaxf(a1.z, 0.f); a1.w = fmaxf(a1.w, 0.f);
        }
        if constexpr (sizeof(OutT) == 2) {
            __half2 p0 = __floats2half2_rn(a0.x, a0.y);
            __half2 p1 = __floats2half2_rn(a0.z, a0.w);
            __half2 p2 = __floats2half2_rn(a1.x, a1.y);
            __half2 p3 = __floats2half2_rn(a1.z, a1.w);
            uint4 pk = make_uint4(*(unsigned int*)&p0, *(unsigned int*)&p1,
                                  *(unsigned int*)&p2, *(unsigned int*)&p3);
            *(uint4*)&out[(size_t)node * F + 8 * lq] = pk;
        } else {
            *(float4*)&out[(size_t)node * F + 8 * lq] = a0;
            *(float4*)&out[(size_t)node * F + 8 * lq + 4] = a1;
        }
    }
}

// ---------------- launch ----------------

extern "C" void kernel_launch(void* const* d_in, const int* in_sizes, int n_in,
                              void* d_out, int out_size, void* d_ws, size_t ws_size,
                              hipStream_t stream) {
    const float* x  = (const float*)d_in[0];
    const int*   ei = (const int*)d_in[1];
    const float* W0 = (const float*)d_in[2];
    const float* b0 = (const float*)d_in[3];
    const float* W1 = (const float*)d_in[4];
    const float* b1 = (const float*)d_in[5];
    const float* W2 = (const float*)d_in[6];
    const float* b2 = (const float*)d_in[7];
    float* out = (float*)d_out;

    const int N = in_sizes[0] / 128;
    const int E = in_sizes[1] / 2;
    const int NBUK = (N + 255) >> 8;   // coarse buckets of 256 nodes (<=512)

    char* w = (char*)d_ws;
    size_t off = 0;
    int*    ccnt      = (int*)(w + off);    off = ALIGN256(off + (size_t)NBUK * 4);
    int*    cbase     = (int*)(w + off);    off = ALIGN256(off + (size_t)(NBUK + 1) * 4);
    int*    cpos      = (int*)(w + off);    off = ALIGN256(off + (size_t)NBUK * 4);
    int*    row_start = (int*)(w + off);    off = ALIGN256(off + (size_t)(N + 1) * 4);
    float*  dinv      = (float*)(w + off);  off = ALIGN256(off + (size_t)N * 4);
    int2*   ep        = (int2*)(w + off);   off = ALIGN256(off + (size_t)E * 8);
    __half* bufH      = (__half*)(w + off); off = ALIGN256(off + (size_t)N * 64 * 2);
    __half* bufG      = (__half*)(w + off); off = ALIGN256(off + (size_t)N * 64 * 2);
    unsigned int* stage = (unsigned int*)bufG;   // dead before agg1 writes bufG

    const int gGemm = (N + 63) / 64;
    const int gAgg  = (N + 31) / 32;
    const int gPA   = (E + 8191) / 8192;

    hipMemsetAsync(ccnt, 0, (size_t)NBUK * 4, stream);
    k_mgemm<128, 64, 4><<<gGemm, 256, 0, stream>>>(x, W0, bufH, N);
    k_coarse<<<gPA, 256, 0, stream>>>(ei, ccnt, E, NBUK);
    k_cscan<<<1, 256, 0, stream>>>(ccnt, cbase, cpos, row_start, NBUK, E, N);
    k_passA<<<gPA, 256, 0, stream>>>(ei, cpos, stage, E, NBUK);
    k_B1<<<NBUK, 256, 0, stream>>>(stage, cbase, row_start, dinv, N);
    k_B2<<<NBUK, 256, 0, stream>>>(stage, cbase, row_start, dinv, ep, N);

    k_agg<8, 64, 1, __half><<<gAgg, 256, 0, stream>>>(bufH, row_start, ep, dinv, b0, bufG, N);
    k_mgemm<64, 64, 4><<<gGemm, 256, 0, stream>>>(bufG, W1, bufH, N);
    k_agg<8, 64, 1, __half><<<gAgg, 256, 0, stream>>>(bufH, row_start, ep, dinv, b1, bufG, N);
    k_mgemm<64, 40, 3><<<gGemm, 256, 0, stream>>>(bufG, W2, bufH, N);
    k_agg<5, 40, 0, float><<<gAgg, 256, 0, stream>>>(bufH, row_start, ep, dinv, b2, out, N);
}